// Round 1
// baseline (670.586 us; speedup 1.0000x reference)
//
#include <hip/hip_runtime.h>
#include <hip/hip_bf16.h>
#include <cmath>

// Problem constants: B=1, C=192, D=H=W=16 (4096 positions), 6 heads x hd=32,
// kernel 5 -> 125 neighbors. hid=384, mlp_h=768. All fp32.

#define NPOS 4096
#define C_CH 192

// ---------------------------------------------------------------------------
// Kernel 1: per-channel sum and sum-of-squares over the 4096 spatial elements
// ---------------------------------------------------------------------------
__global__ __launch_bounds__(256) void stats_kernel(
    const float* __restrict__ x, float* __restrict__ sums, float* __restrict__ sumsq)
{
    int c = blockIdx.x;
    const float4* xc = (const float4*)(x + (size_t)c * NPOS);
    float s = 0.f, s2 = 0.f;
    for (int i = threadIdx.x; i < NPOS / 4; i += 256) {
        float4 v = xc[i];
        s  += v.x + v.y + v.z + v.w;
        s2 += v.x * v.x + v.y * v.y + v.z * v.z + v.w * v.w;
    }
    #pragma unroll
    for (int off = 32; off > 0; off >>= 1) {
        s  += __shfl_down(s, off);
        s2 += __shfl_down(s2, off);
    }
    __shared__ float ls[4], ls2[4];
    int wid = threadIdx.x >> 6;
    if ((threadIdx.x & 63) == 0) { ls[wid] = s; ls2[wid] = s2; }
    __syncthreads();
    if (threadIdx.x == 0) {
        float t = 0.f, t2 = 0.f;
        #pragma unroll
        for (int w = 0; w < 4; w++) { t += ls[w]; t2 += ls2[w]; }
        sums[c] = t; sumsq[c] = t2;
    }
}

// ---------------------------------------------------------------------------
// Kernel 2: tiny adaptive-gate MLP.  gs[c] = scale[c]*sigmoid(...)/rms[c]
// One block, 384 threads.
// ---------------------------------------------------------------------------
__global__ __launch_bounds__(384) void gamma_kernel(
    const float* __restrict__ sums, const float* __restrict__ sumsq,
    const float* __restrict__ scale,
    const float* __restrict__ w1, const float* __restrict__ b1,
    const float* __restrict__ w2, const float* __restrict__ b2,
    float* __restrict__ gs)
{
    __shared__ float stats[C_CH];
    __shared__ float h[384];
    int t = threadIdx.x;
    if (t < C_CH) stats[t] = sums[t] * (1.0f / (float)NPOS);
    __syncthreads();
    {
        float acc = b1[t];
        const float* wr = w1 + (size_t)t * C_CH;
        #pragma unroll 4
        for (int c = 0; c < C_CH; c += 4) {
            float4 w4 = *(const float4*)(wr + c);
            acc += w4.x * stats[c] + w4.y * stats[c + 1] + w4.z * stats[c + 2] + w4.w * stats[c + 3];
        }
        h[t] = fmaxf(acc, 0.0f);
    }
    __syncthreads();
    if (t < C_CH) {
        float acc = b2[t];
        const float* wr = w2 + (size_t)t * 384;
        #pragma unroll 4
        for (int j = 0; j < 384; j += 4) {
            float4 w4 = *(const float4*)(wr + j);
            acc += w4.x * h[j] + w4.y * h[j + 1] + w4.z * h[j + 2] + w4.w * h[j + 3];
        }
        float g = 1.0f / (1.0f + __expf(-acc));
        float rms = sqrtf(sumsq[t] * (1.0f / (float)NPOS) + 1e-6f);
        gs[t] = scale[t] * g / rms;
    }
}

// ---------------------------------------------------------------------------
// Generic GEMM: out[M][4096] = W[M][K] @ (X[K][4096] * gs[k]) + bias, epilogues:
//   EPI 0: qkv scatter into q/k/v buffers laid out [pos][head][hd]
//   EPI 2: out = resid + acc + bias   (row-major [M][4096])
//   EPI 3: out = gelu(acc + bias)     (exact erf gelu)
// Block: 256 threads = 64 positions x 4 row-groups, 4 rows per thread.
// ---------------------------------------------------------------------------
template <int EPI>
__global__ __launch_bounds__(256) void gemm_kernel(
    const float* __restrict__ W, const float* __restrict__ bias,
    const float* __restrict__ X, const float* __restrict__ gs,
    float* __restrict__ out, const float* __restrict__ resid,
    int M, int K)
{
    constexpr int KC = 192;
    __shared__ float xs[KC * 64];   // 48 KB
    __shared__ float wl[16 * KC];   // 12 KB
    int t = threadIdx.x;
    int p = t & 63;        // position within tile
    int rg = t >> 6;       // row group 0..3 (wave-uniform)
    int posBase = blockIdx.x * 64;
    int rowBase = blockIdx.y * 16;

    float acc[4] = {0.f, 0.f, 0.f, 0.f};

    for (int k0 = 0; k0 < K; k0 += KC) {
        // stage X tile (KC x 64), applying per-channel scale if present
        for (int idx = t; idx < KC * 64; idx += 256) {
            int c = idx >> 6, pp = idx & 63;
            float v = X[(size_t)(k0 + c) * NPOS + posBase + pp];
            if (gs) v *= gs[k0 + c];
            xs[idx] = v;
        }
        // stage W tile (16 x KC)
        for (int idx = t; idx < 16 * KC; idx += 256) {
            int r = idx / KC, c = idx - r * KC;
            wl[idx] = W[(size_t)(rowBase + r) * K + k0 + c];
        }
        __syncthreads();
        #pragma unroll 4
        for (int c = 0; c < KC; c++) {
            float xv = xs[c * 64 + p];
            #pragma unroll
            for (int i = 0; i < 4; i++)
                acc[i] += wl[(rg * 4 + i) * KC + c] * xv;
        }
        __syncthreads();
    }

    int pos = posBase + p;
    #pragma unroll
    for (int i = 0; i < 4; i++) {
        int r = rowBase + rg * 4 + i;
        float v = acc[i] + bias[r];
        if (EPI == 0) {
            // r in [0,576): sect 0=q,1=k,2=v ; o = r%192 ; layout [pos][head][32]
            int sect = r / 192;
            int o = r - sect * 192;
            int head = o >> 5, ch = o & 31;
            out[(size_t)sect * (6 * 32 * NPOS) + ((size_t)pos * 6 + head) * 32 + ch] = v;
        } else if (EPI == 2) {
            out[(size_t)r * NPOS + pos] = resid[(size_t)r * NPOS + pos] + v;
        } else {
            // exact gelu: 0.5*v*(1+erf(v/sqrt(2)))
            out[(size_t)r * NPOS + pos] = 0.5f * v * (1.0f + erff(v * 0.7071067811865475f));
        }
    }
}

// ---------------------------------------------------------------------------
// Kernel: neighborhood attention. One thread per (pos, head).
// q/k/v layout [pos][head][32]; output o layout [c'=head*32+ch][pos].
// Online softmax over the 125 neighbors.
// ---------------------------------------------------------------------------
__global__ __launch_bounds__(64) void attn_kernel(
    const float* __restrict__ q, const float* __restrict__ k,
    const float* __restrict__ v, float* __restrict__ o)
{
    int tid = blockIdx.x * 64 + threadIdx.x;   // 0 .. 24575
    int pos = tid / 6;
    int head = tid - pos * 6;
    int wq = pos & 15;
    int hq = (pos >> 4) & 15;
    int dq = pos >> 8;
    int d0 = min(max(dq - 2, 0), 11);
    int h0 = min(max(hq - 2, 0), 11);
    int w0 = min(max(wq - 2, 0), 11);

    const float* kb = k + (size_t)head * 32;
    const float* vb = v + (size_t)head * 32;

    float4 q4[8];
    {
        const float4* qp = (const float4*)(q + ((size_t)pos * 6 + head) * 32);
        #pragma unroll
        for (int i = 0; i < 8; i++) q4[i] = qp[i];
    }

    float m = -1e30f, l = 0.0f;
    float4 acc[8];
    #pragma unroll
    for (int i = 0; i < 8; i++) acc[i] = make_float4(0.f, 0.f, 0.f, 0.f);

    for (int di = 0; di < 5; di++) {
        for (int hi = 0; hi < 5; hi++) {
            #pragma unroll
            for (int wi = 0; wi < 5; wi++) {
                int np = ((d0 + di) * 16 + (h0 + hi)) * 16 + (w0 + wi);
                const float4* kp = (const float4*)(kb + (size_t)np * 192);
                float s = 0.f;
                #pragma unroll
                for (int i = 0; i < 8; i++) {
                    float4 k4 = kp[i];
                    s += q4[i].x * k4.x + q4[i].y * k4.y + q4[i].z * k4.z + q4[i].w * k4.w;
                }
                s *= 0.17677669529663687f;   // 32^-0.5
                float mnew = fmaxf(m, s);
                float sc = __expf(m - mnew);
                float pr = __expf(s - mnew);
                l = l * sc + pr;
                const float4* vp = (const float4*)(vb + (size_t)np * 192);
                #pragma unroll
                for (int i = 0; i < 8; i++) {
                    float4 v4 = vp[i];
                    acc[i].x = acc[i].x * sc + pr * v4.x;
                    acc[i].y = acc[i].y * sc + pr * v4.y;
                    acc[i].z = acc[i].z * sc + pr * v4.z;
                    acc[i].w = acc[i].w * sc + pr * v4.w;
                }
                m = mnew;
            }
        }
    }

    float rl = 1.0f / l;
    float* ob = o + (size_t)(head * 32) * NPOS + pos;
    #pragma unroll
    for (int i = 0; i < 8; i++) {
        ob[(size_t)(i * 4 + 0) * NPOS] = acc[i].x * rl;
        ob[(size_t)(i * 4 + 1) * NPOS] = acc[i].y * rl;
        ob[(size_t)(i * 4 + 2) * NPOS] = acc[i].z * rl;
        ob[(size_t)(i * 4 + 3) * NPOS] = acc[i].w * rl;
    }
}

// ---------------------------------------------------------------------------
extern "C" void kernel_launch(void* const* d_in, const int* in_sizes, int n_in,
                              void* d_out, int out_size, void* d_ws, size_t ws_size,
                              hipStream_t stream)
{
    const float* x      = (const float*)d_in[0];
    const float* scale1 = (const float*)d_in[1];
    const float* n1_w1  = (const float*)d_in[2];
    const float* n1_b1  = (const float*)d_in[3];
    const float* n1_w2  = (const float*)d_in[4];
    const float* n1_b2  = (const float*)d_in[5];
    const float* qkv_w  = (const float*)d_in[6];
    const float* qkv_b  = (const float*)d_in[7];
    const float* proj_w = (const float*)d_in[8];
    const float* proj_b = (const float*)d_in[9];
    const float* scale2 = (const float*)d_in[10];
    const float* n2_w1  = (const float*)d_in[11];
    const float* n2_b1  = (const float*)d_in[12];
    const float* n2_w2  = (const float*)d_in[13];
    const float* n2_b2  = (const float*)d_in[14];
    const float* mlp_w1 = (const float*)d_in[15];
    const float* mlp_b1 = (const float*)d_in[16];
    const float* mlp_w2 = (const float*)d_in[17];
    const float* mlp_b2 = (const float*)d_in[18];

    float* ws = (float*)d_ws;
    // workspace layout (floats):
    //   [0 .. 3145728)      : qkv (q|k|v, 786432 each)  -- later aliased by m (768*4096)
    //   [3145728 .. 3932160): o_attn (192*4096)
    //   [3932160 .. 3932736): sums[192] | sumsq[192] | gs[192]
    float* qkv_buf = ws;
    float* q_buf   = ws;
    float* k_buf   = ws + 786432;
    float* v_buf   = ws + 1572864;
    float* m_buf   = ws;                 // alias: q/k/v dead after attention
    float* o_attn  = ws + 3145728;
    float* sums    = ws + 3932160;
    float* sumsq   = sums + 192;
    float* gsv     = sums + 384;

    float* x2 = (float*)d_out;           // x2 (post-attention residual) lives in d_out

    // ---- norm 1 ----
    stats_kernel<<<192, 256, 0, stream>>>(x, sums, sumsq);
    gamma_kernel<<<1, 384, 0, stream>>>(sums, sumsq, scale1, n1_w1, n1_b1, n1_w2, n1_b2, gsv);
    // ---- qkv projection (576 x 192 @ 192 x 4096) ----
    gemm_kernel<0><<<dim3(64, 36), 256, 0, stream>>>(qkv_w, qkv_b, x, gsv, qkv_buf, nullptr, 576, 192);
    // ---- neighborhood attention ----
    attn_kernel<<<384, 64, 0, stream>>>(q_buf, k_buf, v_buf, o_attn);
    // ---- output projection + residual -> x2 (in d_out) ----
    gemm_kernel<2><<<dim3(64, 12), 256, 0, stream>>>(proj_w, proj_b, o_attn, nullptr, x2, x, 192, 192);
    // ---- norm 2 ----
    stats_kernel<<<192, 256, 0, stream>>>(x2, sums, sumsq);
    gamma_kernel<<<1, 384, 0, stream>>>(sums, sumsq, scale2, n2_w1, n2_b1, n2_w2, n2_b2, gsv);
    // ---- MLP ----
    gemm_kernel<3><<<dim3(64, 48), 256, 0, stream>>>(mlp_w1, mlp_b1, x2, gsv, m_buf, nullptr, 768, 192);
    gemm_kernel<2><<<dim3(64, 12), 256, 0, stream>>>(mlp_w2, mlp_b2, m_buf, nullptr, (float*)d_out, x2, 192, 768);
}

// Round 2
// 281.443 us; speedup vs baseline: 2.3827x; 2.3827x over previous
//
#include <hip/hip_runtime.h>
#include <hip/hip_bf16.h>
#include <cmath>

// B=1, C=192, D=H=W=16 (4096 pos), 6 heads x hd=32, kernel 5 -> 125 neighbors.
// hid=384, mlp_h=768. All fp32.

#define NPOS 4096
#define C_CH 192

// ---------------------------------------------------------------------------
// Kernel 1: per-channel sum and sum-of-squares over the 4096 spatial elements
// ---------------------------------------------------------------------------
__global__ __launch_bounds__(256) void stats_kernel(
    const float* __restrict__ x, float* __restrict__ sums, float* __restrict__ sumsq)
{
    int c = blockIdx.x;
    const float4* xc = (const float4*)(x + (size_t)c * NPOS);
    float s = 0.f, s2 = 0.f;
    for (int i = threadIdx.x; i < NPOS / 4; i += 256) {
        float4 v = xc[i];
        s  += v.x + v.y + v.z + v.w;
        s2 += v.x * v.x + v.y * v.y + v.z * v.z + v.w * v.w;
    }
    #pragma unroll
    for (int off = 32; off > 0; off >>= 1) {
        s  += __shfl_down(s, off);
        s2 += __shfl_down(s2, off);
    }
    __shared__ float ls[4], ls2[4];
    int wid = threadIdx.x >> 6;
    if ((threadIdx.x & 63) == 0) { ls[wid] = s; ls2[wid] = s2; }
    __syncthreads();
    if (threadIdx.x == 0) {
        float t = 0.f, t2 = 0.f;
        #pragma unroll
        for (int w = 0; w < 4; w++) { t += ls[w]; t2 += ls2[w]; }
        sums[c] = t; sumsq[c] = t2;
    }
}

// ---------------------------------------------------------------------------
// Kernel 2: tiny adaptive-gate MLP.  gs[c] = scale[c]*sigmoid(...)/rms[c]
// ---------------------------------------------------------------------------
__global__ __launch_bounds__(384) void gamma_kernel(
    const float* __restrict__ sums, const float* __restrict__ sumsq,
    const float* __restrict__ scale,
    const float* __restrict__ w1, const float* __restrict__ b1,
    const float* __restrict__ w2, const float* __restrict__ b2,
    float* __restrict__ gs)
{
    __shared__ float stats[C_CH];
    __shared__ float h[384];
    int t = threadIdx.x;
    if (t < C_CH) stats[t] = sums[t] * (1.0f / (float)NPOS);
    __syncthreads();
    {
        float acc = b1[t];
        const float* wr = w1 + (size_t)t * C_CH;
        #pragma unroll 4
        for (int c = 0; c < C_CH; c += 4) {
            float4 w4 = *(const float4*)(wr + c);
            acc += w4.x * stats[c] + w4.y * stats[c + 1] + w4.z * stats[c + 2] + w4.w * stats[c + 3];
        }
        h[t] = fmaxf(acc, 0.0f);
    }
    __syncthreads();
    if (t < C_CH) {
        float acc = b2[t];
        const float* wr = w2 + (size_t)t * 384;
        #pragma unroll 4
        for (int j = 0; j < 384; j += 4) {
            float4 w4 = *(const float4*)(wr + j);
            acc += w4.x * h[j] + w4.y * h[j + 1] + w4.z * h[j + 2] + w4.w * h[j + 3];
        }
        float g = 1.0f / (1.0f + __expf(-acc));
        float rms = sqrtf(sumsq[t] * (1.0f / (float)NPOS) + 1e-6f);
        gs[t] = scale[t] * g / rms;
    }
}

// ---------------------------------------------------------------------------
// GEMM: out[M][4096] = W[M][K] @ (X[K][4096] * gs[k]) + bias
// Tile: 64 rows x 64 positions per block, 256 threads, each thread 4x4.
// LDS: xs[c][64 pos] (stride 64), wl[c][64 rows] (stride 68, padded).
// Inner loop per c: 2x ds_read_b128 + 16 v_fmac  -> VALU-bound.
//   EPI 0: qkv scatter into [pos][head][32] (q|k|v sections)
//   EPI 2: out = resid + acc + bias
//   EPI 3: out = exact gelu(acc + bias)
// ---------------------------------------------------------------------------
#define KC 96
#define WLS 68

template <int EPI>
__global__ __launch_bounds__(256) void gemm_kernel(
    const float* __restrict__ W, const float* __restrict__ bias,
    const float* __restrict__ X, const float* __restrict__ gs,
    float* __restrict__ out, const float* __restrict__ resid,
    int M, int K)
{
    __shared__ float xs[KC * 64];    // 24 KB
    __shared__ float wl[KC * WLS];   // ~26 KB
    int t = threadIdx.x;
    int pg = t & 15;       // position group: 4 consecutive positions
    int rg = t >> 4;       // row group: 4 consecutive rows (0..15)
    int posBase = blockIdx.x * 64;
    int rowBase = blockIdx.y * 64;

    float acc[4][4];
    #pragma unroll
    for (int i = 0; i < 4; i++)
        #pragma unroll
        for (int j = 0; j < 4; j++) acc[i][j] = 0.f;

    for (int k0 = 0; k0 < K; k0 += KC) {
        // stage X tile: 96 rows x 16 float4
        #pragma unroll
        for (int it = 0; it < 6; it++) {
            int idx = it * 256 + t;
            int row = idx >> 4, c4 = idx & 15;
            float4 v = *(const float4*)(X + (size_t)(k0 + row) * NPOS + posBase + c4 * 4);
            if (gs) {
                float g = gs[k0 + row];
                v.x *= g; v.y *= g; v.z *= g; v.w *= g;
            }
            *(float4*)(xs + row * 64 + c4 * 4) = v;
        }
        // stage W tile transposed: 64 rows x 24 float4 along K
        #pragma unroll
        for (int it = 0; it < 6; it++) {
            int idx = it * 256 + t;
            int r = idx / 24, q = idx - r * 24;
            float4 w4 = *(const float4*)(W + (size_t)(rowBase + r) * K + k0 + q * 4);
            wl[(q * 4 + 0) * WLS + r] = w4.x;
            wl[(q * 4 + 1) * WLS + r] = w4.y;
            wl[(q * 4 + 2) * WLS + r] = w4.z;
            wl[(q * 4 + 3) * WLS + r] = w4.w;
        }
        __syncthreads();
        #pragma unroll 4
        for (int c = 0; c < KC; c++) {
            float4 xv = *(const float4*)(xs + c * 64 + pg * 4);
            float4 wv = *(const float4*)(wl + c * WLS + rg * 4);
            const float xa[4] = {xv.x, xv.y, xv.z, xv.w};
            const float wa[4] = {wv.x, wv.y, wv.z, wv.w};
            #pragma unroll
            for (int i = 0; i < 4; i++)
                #pragma unroll
                for (int j = 0; j < 4; j++)
                    acc[i][j] += wa[i] * xa[j];
        }
        __syncthreads();
    }

    int pos0 = posBase + pg * 4;
    #pragma unroll
    for (int i = 0; i < 4; i++) {
        int r = rowBase + rg * 4 + i;
        float b = bias[r];
        if (EPI == 0) {
            int sect = r / 192;
            int o = r - sect * 192;
            float* dst = out + (size_t)sect * (192 * NPOS) + o;
            #pragma unroll
            for (int j = 0; j < 4; j++)
                dst[(size_t)(pos0 + j) * 192] = acc[i][j] + b;
        } else if (EPI == 2) {
            float4 rs = *(const float4*)(resid + (size_t)r * NPOS + pos0);
            float4 v = make_float4(acc[i][0] + b + rs.x, acc[i][1] + b + rs.y,
                                   acc[i][2] + b + rs.z, acc[i][3] + b + rs.w);
            *(float4*)(out + (size_t)r * NPOS + pos0) = v;
        } else {
            float4 v;
            float a0 = acc[i][0] + b, a1 = acc[i][1] + b, a2 = acc[i][2] + b, a3 = acc[i][3] + b;
            v.x = 0.5f * a0 * (1.0f + erff(a0 * 0.7071067811865475f));
            v.y = 0.5f * a1 * (1.0f + erff(a1 * 0.7071067811865475f));
            v.z = 0.5f * a2 * (1.0f + erff(a2 * 0.7071067811865475f));
            v.w = 0.5f * a3 * (1.0f + erff(a3 * 0.7071067811865475f));
            *(float4*)(out + (size_t)r * NPOS + pos0) = v;
        }
    }
}

// ---------------------------------------------------------------------------
// Neighborhood attention: 8 lanes per (pos, head); lane owns 4 of 32 channels.
// QK dot reduced with __shfl_xor(1,2,4) (stays within aligned 8-lane groups).
// q/k/v layout [pos][head][32]; output o layout [c'=head*32+ch][pos].
// ---------------------------------------------------------------------------
__global__ __launch_bounds__(256) void attn_kernel(
    const float* __restrict__ q, const float* __restrict__ k,
    const float* __restrict__ v, float* __restrict__ o)
{
    int t = threadIdx.x;
    int pairIdx = blockIdx.x * 32 + (t >> 3);   // 0 .. 24575
    int lane = t & 7;                            // channel group
    int pos = pairIdx / 6;
    int head = pairIdx - pos * 6;
    int wq = pos & 15;
    int hq = (pos >> 4) & 15;
    int dq = pos >> 8;
    int d0 = min(max(dq - 2, 0), 11);
    int h0 = min(max(hq - 2, 0), 11);
    int w0 = min(max(wq - 2, 0), 11);

    const float* kb = k + (size_t)head * 32 + lane * 4;
    const float* vb = v + (size_t)head * 32 + lane * 4;

    float4 q4 = *(const float4*)(q + ((size_t)pos * 6 + head) * 32 + lane * 4);

    float m = -1e30f, l = 0.0f;
    float4 acc = make_float4(0.f, 0.f, 0.f, 0.f);

    for (int di = 0; di < 5; di++) {
        int dbase = (d0 + di) * 256;
        for (int hi = 0; hi < 5; hi++) {
            int hbase = dbase + (h0 + hi) * 16 + w0;
            #pragma unroll
            for (int wi = 0; wi < 5; wi++) {
                int np = hbase + wi;
                float4 k4 = *(const float4*)(kb + (size_t)np * 192);
                float s = q4.x * k4.x + q4.y * k4.y + q4.z * k4.z + q4.w * k4.w;
                s += __shfl_xor(s, 1);
                s += __shfl_xor(s, 2);
                s += __shfl_xor(s, 4);
                s *= 0.17677669529663687f;   // 32^-0.5
                float mnew = fmaxf(m, s);
                float sc = __expf(m - mnew);
                float pr = __expf(s - mnew);
                l = l * sc + pr;
                float4 v4 = *(const float4*)(vb + (size_t)np * 192);
                acc.x = acc.x * sc + pr * v4.x;
                acc.y = acc.y * sc + pr * v4.y;
                acc.z = acc.z * sc + pr * v4.z;
                acc.w = acc.w * sc + pr * v4.w;
                m = mnew;
            }
        }
    }

    float rl = 1.0f / l;
    float* ob = o + (size_t)(head * 32 + lane * 4) * NPOS + pos;
    ob[0]             = acc.x * rl;
    ob[(size_t)NPOS]  = acc.y * rl;
    ob[(size_t)NPOS*2] = acc.z * rl;
    ob[(size_t)NPOS*3] = acc.w * rl;
}

// ---------------------------------------------------------------------------
extern "C" void kernel_launch(void* const* d_in, const int* in_sizes, int n_in,
                              void* d_out, int out_size, void* d_ws, size_t ws_size,
                              hipStream_t stream)
{
    const float* x      = (const float*)d_in[0];
    const float* scale1 = (const float*)d_in[1];
    const float* n1_w1  = (const float*)d_in[2];
    const float* n1_b1  = (const float*)d_in[3];
    const float* n1_w2  = (const float*)d_in[4];
    const float* n1_b2  = (const float*)d_in[5];
    const float* qkv_w  = (const float*)d_in[6];
    const float* qkv_b  = (const float*)d_in[7];
    const float* proj_w = (const float*)d_in[8];
    const float* proj_b = (const float*)d_in[9];
    const float* scale2 = (const float*)d_in[10];
    const float* n2_w1  = (const float*)d_in[11];
    const float* n2_b1  = (const float*)d_in[12];
    const float* n2_w2  = (const float*)d_in[13];
    const float* n2_b2  = (const float*)d_in[14];
    const float* mlp_w1 = (const float*)d_in[15];
    const float* mlp_b1 = (const float*)d_in[16];
    const float* mlp_w2 = (const float*)d_in[17];
    const float* mlp_b2 = (const float*)d_in[18];

    float* ws = (float*)d_ws;
    // ws floats: [0,3145728) q|k|v (786432 each; aliased by m [768][4096] later)
    //            [3145728,3932160) o_attn [192][4096]
    //            [3932160,3932736) sums|sumsq|gs
    float* qkv_buf = ws;
    float* q_buf   = ws;
    float* k_buf   = ws + 786432;
    float* v_buf   = ws + 1572864;
    float* m_buf   = ws;
    float* o_attn  = ws + 3145728;
    float* sums    = ws + 3932160;
    float* sumsq   = sums + 192;
    float* gsv     = sums + 384;

    float* x2 = (float*)d_out;

    stats_kernel<<<192, 256, 0, stream>>>(x, sums, sumsq);
    gamma_kernel<<<1, 384, 0, stream>>>(sums, sumsq, scale1, n1_w1, n1_b1, n1_w2, n1_b2, gsv);
    gemm_kernel<0><<<dim3(64, 9), 256, 0, stream>>>(qkv_w, qkv_b, x, gsv, qkv_buf, nullptr, 576, 192);
    attn_kernel<<<768, 256, 0, stream>>>(q_buf, k_buf, v_buf, o_attn);
    gemm_kernel<2><<<dim3(64, 3), 256, 0, stream>>>(proj_w, proj_b, o_attn, nullptr, x2, x, 192, 192);
    stats_kernel<<<192, 256, 0, stream>>>(x2, sums, sumsq);
    gamma_kernel<<<1, 384, 0, stream>>>(sums, sumsq, scale2, n2_w1, n2_b1, n2_w2, n2_b2, gsv);
    gemm_kernel<3><<<dim3(64, 12), 256, 0, stream>>>(mlp_w1, mlp_b1, x2, gsv, m_buf, nullptr, 768, 192);
    gemm_kernel<2><<<dim3(64, 3), 256, 0, stream>>>(mlp_w2, mlp_b2, m_buf, nullptr, (float*)d_out, x2, 192, 768);
}

// Round 3
// 238.854 us; speedup vs baseline: 2.8075x; 1.1783x over previous
//
#include <hip/hip_runtime.h>
#include <hip/hip_bf16.h>
#include <cmath>

// B=1, C=192, D=H=W=16 (4096 pos), 6 heads x hd=32, kernel 5 -> 125 neighbors.
// hid=384, mlp_h=768. fp32 in/out; GEMMs run bf16-MFMA with fp32 accum.

#define NPOS 4096
#define C_CH 192

typedef __bf16 bf16x8 __attribute__((ext_vector_type(8)));
typedef __bf16 bf16x4 __attribute__((ext_vector_type(4)));
typedef float  f32x4  __attribute__((ext_vector_type(4)));

// ---------------------------------------------------------------------------
// per-channel sum / sumsq over 4096 spatial elements
// ---------------------------------------------------------------------------
__global__ __launch_bounds__(256) void stats_kernel(
    const float* __restrict__ x, float* __restrict__ sums, float* __restrict__ sumsq)
{
    int c = blockIdx.x;
    const float4* xc = (const float4*)(x + (size_t)c * NPOS);
    float s = 0.f, s2 = 0.f;
    for (int i = threadIdx.x; i < NPOS / 4; i += 256) {
        float4 v = xc[i];
        s  += v.x + v.y + v.z + v.w;
        s2 += v.x * v.x + v.y * v.y + v.z * v.z + v.w * v.w;
    }
    #pragma unroll
    for (int off = 32; off > 0; off >>= 1) {
        s  += __shfl_down(s, off);
        s2 += __shfl_down(s2, off);
    }
    __shared__ float ls[4], ls2[4];
    int wid = threadIdx.x >> 6;
    if ((threadIdx.x & 63) == 0) { ls[wid] = s; ls2[wid] = s2; }
    __syncthreads();
    if (threadIdx.x == 0) {
        float t = 0.f, t2 = 0.f;
        #pragma unroll
        for (int w = 0; w < 4; w++) { t += ls[w]; t2 += ls2[w]; }
        sums[c] = t; sumsq[c] = t2;
    }
}

// ---------------------------------------------------------------------------
// tiny adaptive-gate MLP: gs[c] = scale[c]*sigmoid(...)/rms
// ---------------------------------------------------------------------------
__global__ __launch_bounds__(384) void gamma_kernel(
    const float* __restrict__ sums, const float* __restrict__ sumsq,
    const float* __restrict__ scale,
    const float* __restrict__ w1, const float* __restrict__ b1,
    const float* __restrict__ w2, const float* __restrict__ b2,
    float* __restrict__ gs)
{
    __shared__ float stats[C_CH];
    __shared__ float h[384];
    int t = threadIdx.x;
    if (t < C_CH) stats[t] = sums[t] * (1.0f / (float)NPOS);
    __syncthreads();
    {
        float acc = b1[t];
        const float* wr = w1 + (size_t)t * C_CH;
        #pragma unroll 4
        for (int c = 0; c < C_CH; c += 4) {
            float4 w4 = *(const float4*)(wr + c);
            acc += w4.x * stats[c] + w4.y * stats[c + 1] + w4.z * stats[c + 2] + w4.w * stats[c + 3];
        }
        h[t] = fmaxf(acc, 0.0f);
    }
    __syncthreads();
    if (t < C_CH) {
        float acc = b2[t];
        const float* wr = w2 + (size_t)t * 384;
        #pragma unroll 4
        for (int j = 0; j < 384; j += 4) {
            float4 w4 = *(const float4*)(wr + j);
            acc += w4.x * h[j] + w4.y * h[j + 1] + w4.z * h[j + 2] + w4.w * h[j + 3];
        }
        float g = 1.0f / (1.0f + __expf(-acc));
        float rms = sqrtf(sumsq[t] * (1.0f / (float)NPOS) + 1e-6f);
        gs[t] = scale[t] * g / rms;
    }
}

// ---------------------------------------------------------------------------
// weight fp32 -> bf16 conversion (all 4 weights in one launch, block=1024 elems)
// segs (float4 blocks of 256): qkv 108 | proj 36 | mlp1 144 | mlp2 144
// ---------------------------------------------------------------------------
__global__ __launch_bounds__(256) void convw_kernel(
    const float* __restrict__ s0, const float* __restrict__ s1,
    const float* __restrict__ s2, const float* __restrict__ s3,
    __bf16* __restrict__ d0, __bf16* __restrict__ d1,
    __bf16* __restrict__ d2, __bf16* __restrict__ d3)
{
    int b = blockIdx.x;
    const float* s; __bf16* d; int base;
    if (b < 108)      { s = s0; d = d0; base = b; }
    else if (b < 144) { s = s1; d = d1; base = b - 108; }
    else if (b < 288) { s = s2; d = d2; base = b - 144; }
    else              { s = s3; d = d3; base = b - 288; }
    int i = (base * 256 + threadIdx.x) * 4;
    float4 v = *(const float4*)(s + i);
    bf16x4 o = { (__bf16)v.x, (__bf16)v.y, (__bf16)v.z, (__bf16)v.w };
    *(bf16x4*)(d + i) = o;
}

// ---------------------------------------------------------------------------
// xb[pos][192] = bf16(x[c][pos] * gs[c])  -- transpose + scale + convert
// one block per 64 positions; LDS tile 192x64 (stride 65 to dodge banks)
// ---------------------------------------------------------------------------
__global__ __launch_bounds__(256) void convx_kernel(
    const float* __restrict__ x, const float* __restrict__ gs, __bf16* __restrict__ xb)
{
    __shared__ float lds[192 * 65];
    int t = threadIdx.x;
    int p0 = blockIdx.x * 64;
    for (int idx = t; idx < 192 * 16; idx += 256) {
        int row = idx >> 4, p4 = idx & 15;
        float4 v = *(const float4*)(x + (size_t)row * NPOS + p0 + p4 * 4);
        float g = gs[row];
        lds[row * 65 + p4 * 4 + 0] = v.x * g;
        lds[row * 65 + p4 * 4 + 1] = v.y * g;
        lds[row * 65 + p4 * 4 + 2] = v.z * g;
        lds[row * 65 + p4 * 4 + 3] = v.w * g;
    }
    __syncthreads();
    for (int idx = t; idx < 48 * 64; idx += 256) {
        int c4 = idx >> 6, p = idx & 63;
        bf16x4 o;
        #pragma unroll
        for (int j = 0; j < 4; j++) o[j] = (__bf16)lds[(c4 * 4 + j) * 65 + p];
        *(bf16x4*)(xb + (size_t)(p0 + p) * 192 + c4 * 4) = o;
    }
}

// ---------------------------------------------------------------------------
// MFMA GEMM: out[M][4096] = W[M][K] @ X^T  with X stored [4096][K] bf16.
// Block 256 thr = 4 waves; block tile 64(M) x 128(N); wave: 64x32 (4x2 tiles).
// No LDS: A frag = W[m=lane&15][quad*8+j] (16B/lane), B frag symmetric.
//   EPI 0: qkv scatter -> q|k|v fp32 [pos][192]
//   EPI 2: out fp32 [M][4096] = acc + bias + resid
//   EPI 3: out bf16 [4096][M] = gelu(acc + bias)
// ---------------------------------------------------------------------------
template <int K, int EPI>
__global__ __launch_bounds__(256) void mfma_gemm(
    const __bf16* __restrict__ W, const float* __restrict__ bias,
    const __bf16* __restrict__ X, void* __restrict__ out,
    const float* __restrict__ resid, int M)
{
    int lane = threadIdx.x & 63;
    int wv   = threadIdx.x >> 6;
    int r16  = lane & 15;
    int quad = lane >> 4;
    int mBase = blockIdx.y * 64;
    int nBase = blockIdx.x * 128 + wv * 32;

    f32x4 acc[4][2];
    #pragma unroll
    for (int i = 0; i < 4; i++)
        #pragma unroll
        for (int j = 0; j < 2; j++)
            acc[i][j] = (f32x4){0.f, 0.f, 0.f, 0.f};

    const __bf16* wp = W + (size_t)(mBase + r16) * K + quad * 8;
    const __bf16* xp = X + (size_t)(nBase + r16) * K + quad * 8;

    #pragma unroll
    for (int ks = 0; ks < K / 32; ks++) {
        bf16x8 a[4], b[2];
        #pragma unroll
        for (int rt = 0; rt < 4; rt++)
            a[rt] = *(const bf16x8*)(wp + (size_t)rt * 16 * K + ks * 32);
        #pragma unroll
        for (int ct = 0; ct < 2; ct++)
            b[ct] = *(const bf16x8*)(xp + (size_t)ct * 16 * K + ks * 32);
        #pragma unroll
        for (int rt = 0; rt < 4; rt++)
            #pragma unroll
            for (int ct = 0; ct < 2; ct++)
                acc[rt][ct] = __builtin_amdgcn_mfma_f32_16x16x32_bf16(a[rt], b[ct], acc[rt][ct], 0, 0, 0);
    }

    #pragma unroll
    for (int rt = 0; rt < 4; rt++) {
        int m0 = mBase + rt * 16 + quad * 4;   // 4 consecutive rows per lane
        float b0 = bias[m0], b1 = bias[m0 + 1], b2 = bias[m0 + 2], b3 = bias[m0 + 3];
        #pragma unroll
        for (int ct = 0; ct < 2; ct++) {
            int n = nBase + ct * 16 + r16;
            f32x4 a4 = acc[rt][ct];
            if (EPI == 0) {
                int sect = m0 / 192;
                int o0 = m0 - sect * 192;
                float4 v = make_float4(a4[0] + b0, a4[1] + b1, a4[2] + b2, a4[3] + b3);
                *(float4*)((float*)out + (size_t)sect * (192 * NPOS) + (size_t)n * 192 + o0) = v;
            } else if (EPI == 2) {
                float* o = (float*)out;
                size_t i0 = (size_t)m0 * NPOS + n;
                o[i0]            = a4[0] + b0 + resid[i0];
                o[i0 + NPOS]     = a4[1] + b1 + resid[i0 + NPOS];
                o[i0 + 2 * NPOS] = a4[2] + b2 + resid[i0 + 2 * NPOS];
                o[i0 + 3 * NPOS] = a4[3] + b3 + resid[i0 + 3 * NPOS];
            } else {
                float g0 = a4[0] + b0, g1 = a4[1] + b1, g2 = a4[2] + b2, g3 = a4[3] + b3;
                bf16x4 v;
                v[0] = (__bf16)(0.5f * g0 * (1.0f + erff(g0 * 0.7071067811865475f)));
                v[1] = (__bf16)(0.5f * g1 * (1.0f + erff(g1 * 0.7071067811865475f)));
                v[2] = (__bf16)(0.5f * g2 * (1.0f + erff(g2 * 0.7071067811865475f)));
                v[3] = (__bf16)(0.5f * g3 * (1.0f + erff(g3 * 0.7071067811865475f)));
                *(bf16x4*)((__bf16*)out + (size_t)n * M + m0) = v;
            }
        }
    }
}

// ---------------------------------------------------------------------------
// Neighborhood attention: 8 lanes per (pos, head); lane owns 4 of 32 channels.
// q/k/v fp32 [pos][192]; output bf16 [pos][192].
// ---------------------------------------------------------------------------
__global__ __launch_bounds__(256) void attn_kernel(
    const float* __restrict__ q, const float* __restrict__ k,
    const float* __restrict__ v, __bf16* __restrict__ o)
{
    int t = threadIdx.x;
    int pairIdx = blockIdx.x * 32 + (t >> 3);
    int lane = t & 7;
    int pos = pairIdx / 6;
    int head = pairIdx - pos * 6;
    int wq = pos & 15;
    int hq = (pos >> 4) & 15;
    int dq = pos >> 8;
    int d0 = min(max(dq - 2, 0), 11);
    int h0 = min(max(hq - 2, 0), 11);
    int w0 = min(max(wq - 2, 0), 11);

    const float* kb = k + (size_t)head * 32 + lane * 4;
    const float* vb = v + (size_t)head * 32 + lane * 4;

    float4 q4 = *(const float4*)(q + ((size_t)pos * 6 + head) * 32 + lane * 4);
    // NOTE: q/k/v are [pos][192]=[pos][head*32+ch]; head*32 ok since 6*32=192
    // (pos*6+head)*32 == pos*192 + head*32

    float m = -1e30f, l = 0.0f;
    float4 acc = make_float4(0.f, 0.f, 0.f, 0.f);

    for (int di = 0; di < 5; di++) {
        int dbase = (d0 + di) * 256;
        for (int hi = 0; hi < 5; hi++) {
            int hbase = dbase + (h0 + hi) * 16 + w0;
            #pragma unroll
            for (int wi = 0; wi < 5; wi++) {
                int np = hbase + wi;
                float4 k4 = *(const float4*)(kb + (size_t)np * 192);
                float s = q4.x * k4.x + q4.y * k4.y + q4.z * k4.z + q4.w * k4.w;
                s += __shfl_xor(s, 1);
                s += __shfl_xor(s, 2);
                s += __shfl_xor(s, 4);
                s *= 0.17677669529663687f;
                float mnew = fmaxf(m, s);
                float sc = __expf(m - mnew);
                float pr = __expf(s - mnew);
                l = l * sc + pr;
                float4 v4 = *(const float4*)(vb + (size_t)np * 192);
                acc.x = acc.x * sc + pr * v4.x;
                acc.y = acc.y * sc + pr * v4.y;
                acc.z = acc.z * sc + pr * v4.z;
                acc.w = acc.w * sc + pr * v4.w;
                m = mnew;
            }
        }
    }

    float rl = 1.0f / l;
    bf16x4 ov = { (__bf16)(acc.x * rl), (__bf16)(acc.y * rl),
                  (__bf16)(acc.z * rl), (__bf16)(acc.w * rl) };
    *(bf16x4*)(o + (size_t)pos * 192 + head * 32 + lane * 4) = ov;
}

// ---------------------------------------------------------------------------
extern "C" void kernel_launch(void* const* d_in, const int* in_sizes, int n_in,
                              void* d_out, int out_size, void* d_ws, size_t ws_size,
                              hipStream_t stream)
{
    const float* x      = (const float*)d_in[0];
    const float* scale1 = (const float*)d_in[1];
    const float* n1_w1  = (const float*)d_in[2];
    const float* n1_b1  = (const float*)d_in[3];
    const float* n1_w2  = (const float*)d_in[4];
    const float* n1_b2  = (const float*)d_in[5];
    const float* qkv_w  = (const float*)d_in[6];
    const float* qkv_b  = (const float*)d_in[7];
    const float* proj_w = (const float*)d_in[8];
    const float* proj_b = (const float*)d_in[9];
    const float* scale2 = (const float*)d_in[10];
    const float* n2_w1  = (const float*)d_in[11];
    const float* n2_b1  = (const float*)d_in[12];
    const float* n2_w2  = (const float*)d_in[13];
    const float* n2_b2  = (const float*)d_in[14];
    const float* mlp_w1 = (const float*)d_in[15];
    const float* mlp_b1 = (const float*)d_in[16];
    const float* mlp_w2 = (const float*)d_in[17];
    const float* mlp_b2 = (const float*)d_in[18];

    float* ws = (float*)d_ws;
    // ws floats:
    //  [0, 2359296)        q|k|v fp32 (786432 each); later aliased by m_buf bf16 [4096][768]
    //  [2359296, 2752512)  xb / xb2 bf16 [4096][192]
    //  [2752512, 3145728)  o_attn bf16 [4096][192]
    //  [3145728, 3366912)  weights bf16: qkv|proj|mlp1|mlp2
    //  [3366912, 3367488)  sums | sumsq | gs
    float*  q_buf  = ws;
    float*  k_buf  = ws + 786432;
    float*  v_buf  = ws + 1572864;
    __bf16* m_buf  = (__bf16*)ws;
    __bf16* xb     = (__bf16*)(ws + 2359296);
    __bf16* o_attn = (__bf16*)(ws + 2752512);
    __bf16* qkv_wb = (__bf16*)(ws + 3145728);
    __bf16* proj_wb = qkv_wb + 110592;
    __bf16* m1_wb   = proj_wb + 36864;
    __bf16* m2_wb   = m1_wb + 147456;
    float*  sums   = ws + 3366912;
    float*  sumsq  = sums + 192;
    float*  gsv    = sums + 384;

    float* x2 = (float*)d_out;

    convw_kernel<<<432, 256, 0, stream>>>(qkv_w, proj_w, mlp_w1, mlp_w2,
                                          qkv_wb, proj_wb, m1_wb, m2_wb);
    stats_kernel<<<192, 256, 0, stream>>>(x, sums, sumsq);
    gamma_kernel<<<1, 384, 0, stream>>>(sums, sumsq, scale1, n1_w1, n1_b1, n1_w2, n1_b2, gsv);
    convx_kernel<<<64, 256, 0, stream>>>(x, gsv, xb);
    mfma_gemm<192, 0><<<dim3(32, 9), 256, 0, stream>>>(qkv_wb, qkv_b, xb, (void*)q_buf, nullptr, 576);
    attn_kernel<<<768, 256, 0, stream>>>(q_buf, k_buf, v_buf, o_attn);
    mfma_gemm<192, 2><<<dim3(32, 3), 256, 0, stream>>>(proj_wb, proj_b, o_attn, (void*)x2, x, 192);
    stats_kernel<<<192, 256, 0, stream>>>(x2, sums, sumsq);
    gamma_kernel<<<1, 384, 0, stream>>>(sums, sumsq, scale2, n2_w1, n2_b1, n2_w2, n2_b2, gsv);
    convx_kernel<<<64, 256, 0, stream>>>(x2, gsv, xb);
    mfma_gemm<192, 3><<<dim3(32, 12), 256, 0, stream>>>(m1_wb, mlp_b1, xb, (void*)m_buf, nullptr, 768);
    mfma_gemm<768, 2><<<dim3(32, 3), 256, 0, stream>>>(m2_wb, mlp_b2, m_buf, (void*)x2, x2, 192);
}